// Round 5
// baseline (90.418 us; speedup 1.0000x reference)
//
#include <hip/hip_runtime.h>
#include <hip/hip_bf16.h>

#define NB 4
#define NL 1024
#define NH 16
#define ND 1024
#define HD 64
#define FMIN_F32 (-3.4028234663852886e38f)
#define LOG2E 1.4426950408889634f

typedef __bf16 bf16x8 __attribute__((ext_vector_type(8)));
typedef float f32x4 __attribute__((ext_vector_type(4)));
typedef unsigned int u32;

static __device__ inline unsigned short f2bf(float f) {
    __hip_bfloat16 h = __float2bfloat16(f);
    return __builtin_bit_cast(unsigned short, h);
}

// split f32 into bf16 hi + bf16 lo (x ~= hi + lo, error ~2^-18 rel)
static __device__ inline void bfsplit(float x, unsigned short& hi, unsigned short& lo) {
    unsigned u = __builtin_bit_cast(unsigned, x);
    unsigned r = (u + 0x7FFFu + ((u >> 16) & 1u)) >> 16;
    hi = (unsigned short)r;
    float hf = __builtin_bit_cast(float, r << 16);
    lo = f2bf(x - hf);
}

// async global->LDS, 16B per lane. LDS dest = firstlane(lds)+lane*16.
static __device__ __forceinline__ void gload16(void* lds, const void* g) {
    __builtin_amdgcn_global_load_lds(
        (const __attribute__((address_space(1))) u32*)g,
        (__attribute__((address_space(3))) u32*)lds, 16, 0, 0);
}

// ---------------------------------------------------------------------------
// Kernel 1: row sums of query/key/value.
// ---------------------------------------------------------------------------
__global__ __launch_bounds__(256)
void rowsum_kernel(const float* __restrict__ q, const float* __restrict__ k,
                   const float* __restrict__ v, float* __restrict__ out) {
    int gw   = blockIdx.x * 4 + (threadIdx.x >> 6);
    int lane = threadIdx.x & 63;
    int tensor = gw >> 12;
    int row    = gw & 4095;
    const float* src = tensor == 0 ? q : (tensor == 1 ? k : v);
    const float* p = src + (size_t)row * ND;
    float s = 0.f;
#pragma unroll
    for (int t = 0; t < 4; ++t) {
        float4 x = *reinterpret_cast<const float4*>(p + t * 256 + lane * 4);
        s += (x.x + x.y) + (x.z + x.w);
    }
#pragma unroll
    for (int off = 32; off; off >>= 1) s += __shfl_xor(s, off);
    if (lane == 0) out[tensor * (NB * NL) + row] = s;
}

// ---------------------------------------------------------------------------
// Kernel 2: prep — pre-swizzled operand tiles + causal suffix table.
//  blocks [0,256):   k_w -> kPhi/kPlo  [h][jt] 8KB tiles, (j_local, s)
//  blocks [256,512): v_w -> vP         [h][jt] 8KB tiles, (t, j_local) (transposed)
//  blocks [512,640): o_w -> BP         [ot][kt] 16KB tiles, (o, c) (transposed)
//  blocks [640,656): SUF[h][s][b][t] = sum_{jt>=s+1} sum_{j in jt} vs_b[j]*V_h[j][t]
// ---------------------------------------------------------------------------
__global__ __launch_bounds__(256)
void prep_kernel(const float* __restrict__ k_w, const float* __restrict__ v_w,
                 const float* __restrict__ o_w, const float* __restrict__ sums,
                 unsigned short* __restrict__ kPhi, unsigned short* __restrict__ kPlo,
                 unsigned short* __restrict__ vP, unsigned short* __restrict__ BP,
                 float* __restrict__ SUF) {
    __shared__ float tile[64][132];
    const int tid = threadIdx.x;
    const int bx  = blockIdx.x;
    if (bx < 256) {
        const int h = bx >> 4, jt = bx & 15;
        char* hiT = (char*)kPhi + (size_t)(h * 16 + jt) * 8192;
        char* loT = (char*)kPlo + (size_t)(h * 16 + jt) * 8192;
        const int row = tid >> 2;
        const int s0  = (tid & 3) * 16;
        const float* src = k_w + ((size_t)(h * NL + jt * 64 + row)) * HD + s0;
#pragma unroll
        for (int t = 0; t < 4; ++t) {
            float4 x = reinterpret_cast<const float4*>(src)[t];
            unsigned short h0, h1, h2, h3, l0, l1, l2, l3;
            bfsplit(x.x, h0, l0); bfsplit(x.y, h1, l1);
            bfsplit(x.z, h2, l2); bfsplit(x.w, h3, l3);
            int off = (row * 128 + (s0 + 4 * t) * 2) ^ ((row & 7) << 4);
            *(uint2*)(hiT + off) = make_uint2((u32)h0 | ((u32)h1 << 16),
                                              (u32)h2 | ((u32)h3 << 16));
            *(uint2*)(loT + off) = make_uint2((u32)l0 | ((u32)l1 << 16),
                                              (u32)l2 | ((u32)l3 << 16));
        }
    } else if (bx < 512) {
        const int h = (bx - 256) >> 4, jt = (bx - 256) & 15;
#pragma unroll
        for (int t = 0; t < 4; ++t) {
            int id = tid + 256 * t;
            int j = id >> 4, t4 = (id & 15) * 4;
            *(float4*)&tile[j][t4] =
                *(const float4*)(v_w + ((size_t)(h * NL + jt * 64 + j)) * HD + t4);
        }
        __syncthreads();
        char* vT_ = (char*)vP + (size_t)(h * 16 + jt) * 8192;
        const int trow = tid >> 2;
        const int jq   = (tid & 3) * 16;
#pragma unroll
        for (int q = 0; q < 4; ++q) {
            int j4 = jq + 4 * q;
            uint2 u;
            u.x = (u32)f2bf(tile[j4 + 0][trow]) | ((u32)f2bf(tile[j4 + 1][trow]) << 16);
            u.y = (u32)f2bf(tile[j4 + 2][trow]) | ((u32)f2bf(tile[j4 + 3][trow]) << 16);
            int off = (trow * 128 + j4 * 2) ^ ((trow & 7) << 4);
            *(uint2*)(vT_ + off) = u;
        }
    } else if (bx < 640) {
        const int bxo = bx - 512;
        const int ot = bxo >> 4, kt = bxo & 15;
#pragma unroll
        for (int t = 0; t < 8; ++t) {
            int id = tid + 256 * t;
            int c = id >> 5, o4 = (id & 31) * 4;
            *(float4*)&tile[c][o4] =
                *(const float4*)(o_w + ((size_t)(kt * 64 + c)) * ND + ot * 128 + o4);
        }
        __syncthreads();
        char* bT = (char*)BP + (size_t)(ot * 16 + kt) * 16384;
#pragma unroll
        for (int t = 0; t < 8; ++t) {
            int id = tid + 256 * t;
            int ol = id >> 4, c4 = (id & 15) * 4;
            uint2 u;
            u.x = (u32)f2bf(tile[c4 + 0][ol]) | ((u32)f2bf(tile[c4 + 1][ol]) << 16);
            u.y = (u32)f2bf(tile[c4 + 2][ol]) | ((u32)f2bf(tile[c4 + 3][ol]) << 16);
            int off = (ol * 128 + c4 * 2) ^ ((ol & 7) << 4);
            *(uint2*)(bT + off) = u;
        }
    } else {
        // causal suffix sums: SUF[h][jt-1][b][t] = sum_{jt'>=jt} vs_b . V_h[:,t]
        const int h = bx - 640;
        const int b = tid >> 6, t = tid & 63;
        const float* vs = sums + 2 * NB * NL + b * NL;
        float acc = 0.f;
        for (int jt = 15; jt >= 1; --jt) {
            const float* vw = v_w + ((size_t)(h * NL + jt * 64)) * HD + t;
            float a = 0.f;
#pragma unroll 16
            for (int j = 0; j < 64; ++j)
                a = fmaf(vs[jt * 64 + j], vw[(size_t)j * HD], a);
            acc += a;
            SUF[(((size_t)h * 16 + (jt - 1)) * 4 + b) * 64 + t] = acc;
        }
    }
}

// ---------------------------------------------------------------------------
// Kernel 3: fused attn with causal-tile skip.
// 512 threads (8 waves), TI=32, TJ=64. 1D grid 512 = (itile 32) x (h 16),
// remapped so block pairs (bx, bx+256) have complementary work.
// Processes jt in [0, cut); the fully-masked suffix is 0.25*SUF added at end.
// ---------------------------------------------------------------------------
__global__ __launch_bounds__(512, 4)
void attn_kernel(const float* __restrict__ q_w, const int* __restrict__ pad,
                 const float* __restrict__ sums,
                 const unsigned short* __restrict__ kPhi,
                 const unsigned short* __restrict__ kPlo,
                 const unsigned short* __restrict__ vP,
                 const float* __restrict__ SUF,
                 unsigned short* __restrict__ AP) {
    __shared__ __align__(16) unsigned short kHi[2][4096], kLo[2][4096], vTl[2][4096];
    __shared__ __align__(16) unsigned short qHi[2048], qLo[2048];
    __shared__ __align__(16) unsigned short wlds[8192];
    __shared__ __align__(16) float qs4[128];
    __shared__ __align__(16) float ks4[2][256];
    __shared__ __align__(16) float vs4[2][256];
    __shared__ __align__(16) int   pm4[2][256];

    const float* qsum = sums;
    const float* ksum = sums + NB * NL;
    const float* vsum = sums + 2 * NB * NL;

    const int wid = blockIdx.x;
    const int gq  = wid >> 4;
    const int h   = wid & 15;
    const int itp = (gq < 16) ? (2 * gq) : (63 - 2 * gq);  // work-balanced remap
    const int it0 = itp * 32;
    const int cut = (it0 >> 6) + 1;      // tiles [0,cut) have unmasked positions

    const int tid  = threadIdx.x;
    const int lane = tid & 63;
    const int w    = tid >> 6;
    const int l15  = lane & 15;
    const int kb   = (lane >> 4) * 16;

    // ---- stage q tile (f32 -> bf16 hi/lo, swizzled), once ----
    {
        int row = tid >> 4;
        int s4  = (tid & 15) * 4;
        float4 x = *(const float4*)(q_w + ((size_t)(h * NL + it0 + row)) * HD + s4);
        unsigned short h0, h1, h2, h3, l0, l1, l2, l3;
        bfsplit(x.x, h0, l0); bfsplit(x.y, h1, l1);
        bfsplit(x.z, h2, l2); bfsplit(x.w, h3, l3);
        int off = (row * 128 + s4 * 2) ^ ((row & 7) << 4);
        *(uint2*)((char*)qHi + off) = make_uint2((u32)h0 | ((u32)h1 << 16),
                                                 (u32)h2 | ((u32)h3 << 16));
        *(uint2*)((char*)qLo + off) = make_uint2((u32)l0 | ((u32)l1 << 16),
                                                 (u32)l2 | ((u32)l3 << 16));
    }
    if (tid < 128) {
        int b = tid >> 5, i = tid & 31;
        qs4[i * 4 + b] = qsum[b * NL + it0 + i];
    }

    auto stage = [&](int buf, int jt) {
        const size_t tb = (size_t)(h * 16 + jt) * 8192 + tid * 16;
        gload16((char*)kHi[buf] + tid * 16, (const char*)kPhi + tb);
        gload16((char*)kLo[buf] + tid * 16, (const char*)kPlo + tb);
        gload16((char*)vTl[buf] + tid * 16, (const char*)vP + tb);
        if (tid < 256) {
            int b = tid >> 6, jj = tid & 63;
            ks4[buf][jj * 4 + b] = ksum[b * NL + jt * 64 + jj] * LOG2E;
            vs4[buf][jj * 4 + b] = vsum[b * NL + jt * 64 + jj];
            pm4[buf][jj * 4 + b] = pad[b * NL + jt * 64 + jj];
        }
    };

    const int gmi = (w & 1) * 16;
    const int gnj = (w >> 1) * 16;
    const int pb  = w >> 1;
    const int pmh = (w & 1) * 16;

    f32x4 accP[4];
#pragma unroll
    for (int n = 0; n < 4; ++n) accP[n] = (f32x4){0.f, 0.f, 0.f, 0.f};

    stage(0, 0);
    __syncthreads();
    int cur = 0;

    for (int jt = 0; jt < cut; ++jt) {
        const int j0 = jt * 64;
        if (jt + 1 < cut) stage(cur ^ 1, jt + 1);

        // ---- G: one 16x16 fragment per wave, bf16x3 ----
        f32x4 g = (f32x4){0.f, 0.f, 0.f, 0.f};
#pragma unroll
        for (int ks = 0; ks < 2; ++ks) {
            const int arow = gmi + l15;
            const int brow = gnj + l15;
            const int aoff = (arow * 128 + ks * 64 + kb) ^ ((arow & 7) << 4);
            const int boff = (brow * 128 + ks * 64 + kb) ^ ((brow & 7) << 4);
            bf16x8 aHi = __builtin_bit_cast(bf16x8, *(const uint4*)((const char*)qHi + aoff));
            bf16x8 aLo = __builtin_bit_cast(bf16x8, *(const uint4*)((const char*)qLo + aoff));
            bf16x8 bHi = __builtin_bit_cast(bf16x8, *(const uint4*)((const char*)kHi[cur] + boff));
            bf16x8 bLo = __builtin_bit_cast(bf16x8, *(const uint4*)((const char*)kLo[cur] + boff));
            g = __builtin_amdgcn_mfma_f32_16x16x32_bf16(aHi, bHi, g, 0, 0, 0);
            g = __builtin_amdgcn_mfma_f32_16x16x32_bf16(aLo, bHi, g, 0, 0, 0);
            g = __builtin_amdgcn_mfma_f32_16x16x32_bf16(aHi, bLo, g, 0, 0, 0);
        }

        // ---- per-lane 4-batch softmax (exp2 domain) -> bf16 weights*vsum ----
        {
            const int j  = gnj + l15;
            const int jg = j0 + j;
            const float4 ksv = *(const float4*)&ks4[cur][j * 4];
            const float4 vsv = *(const float4*)&vs4[cur][j * 4];
            const int4   pmv = *(const int4*)&pm4[cur][j * 4];
#pragma unroll
            for (int r = 0; r < 4; ++r) {
                const int il = gmi + (lane >> 4) * 4 + r;
                const int ig = it0 + il;
                const float gv = g[r] * 0.25f;
                const float4 qsv = *(const float4*)&qs4[il * 4];
                const bool causal = jg > ig;
                const float sb0 = (causal || pmv.x) ? FMIN_F32 : qsv.x * ksv.x * gv;
                const float sb1 = (causal || pmv.y) ? FMIN_F32 : qsv.y * ksv.y * gv;
                const float sb2 = (causal || pmv.z) ? FMIN_F32 : qsv.z * ksv.z * gv;
                const float sb3 = (causal || pmv.w) ? FMIN_F32 : qsv.w * ksv.w * gv;
                const float mx = fmaxf(fmaxf(sb0, sb1), fmaxf(sb2, sb3));
                const float e0 = __builtin_amdgcn_exp2f(sb0 - mx);
                const float e1 = __builtin_amdgcn_exp2f(sb1 - mx);
                const float e2 = __builtin_amdgcn_exp2f(sb2 - mx);
                const float e3 = __builtin_amdgcn_exp2f(sb3 - mx);
                const float inv = __builtin_amdgcn_rcpf((e0 + e1) + (e2 + e3));
                const int off = (il * 128 + j * 2) ^ ((il & 7) << 4);
                *(unsigned short*)((char*)wlds + off)         = f2bf(e0 * inv * vsv.x);
                *(unsigned short*)((char*)wlds + 4096 + off)  = f2bf(e1 * inv * vsv.y);
                *(unsigned short*)((char*)wlds + 8192 + off)  = f2bf(e2 * inv * vsv.z);
                *(unsigned short*)((char*)wlds + 12288 + off) = f2bf(e3 * inv * vsv.w);
            }
        }
        __syncthreads();   // wlds ready; staging drained

        // ---- PV: wave (pb, pmh): 16 i-rows x 64 t for batch pb ----
#pragma unroll
        for (int ks = 0; ks < 2; ++ks) {
            const int arow = pmh + l15;
            const int aoff = pb * 4096 + ((arow * 128 + ks * 64 + kb) ^ ((arow & 7) << 4));
            bf16x8 aF = __builtin_bit_cast(bf16x8, *(const uint4*)((const char*)wlds + aoff));
#pragma unroll
            for (int n = 0; n < 4; ++n) {
                const int vrow = n * 16 + l15;
                const int voff = (vrow * 128 + ks * 64 + kb) ^ ((vrow & 7) << 4);
                bf16x8 bF = __builtin_bit_cast(bf16x8, *(const uint4*)((const char*)vTl[cur] + voff));
                accP[n] = __builtin_amdgcn_mfma_f32_16x16x32_bf16(aF, bF, accP[n], 0, 0, 0);
            }
        }
        __syncthreads();   // PV done reading wlds/vTl before next overwrite
        cur ^= 1;
    }

    // ---- add fully-masked causal suffix: 0.25 * SUF[h][cut-1][pb][t] ----
    if (cut < 16) {
        const float* sp = SUF + (((size_t)h * 16 + (cut - 1)) * 4 + pb) * 64;
#pragma unroll
        for (int n = 0; n < 4; ++n) {
            const float sv = 0.25f * sp[n * 16 + l15];
#pragma unroll
            for (int r = 0; r < 4; ++r) accP[n][r] += sv;
        }
    }

    // ---- store AP tiles (pre-swizzled out-GEMM A layout, bf16) ----
    {
        const int ib = (it0 + pmh) >> 4;
        char* tbase = (char*)AP + (size_t)((pb * 16 + h) * 16) * 8192;
#pragma unroll
        for (int n = 0; n < 4; ++n)
#pragma unroll
            for (int r = 0; r < 4; ++r) {
                int kt = (lane >> 4) * 4 + r;
                int tt = n * 16 + l15;
                int off = (ib * 128 + tt * 2) ^ ((ib & 7) << 4);
                *(unsigned short*)(tbase + (size_t)kt * 8192 + off) = f2bf(accP[n][r]);
            }
    }
}

// ---------------------------------------------------------------------------
// Kernel 4: out(4096x1024) = AP(4096x1024 bf16) @ BP(1024x1024 bf16 [o][c]^T).
// 64x128 tiles, grid (8, 64) = 512 blocks, 256 threads, BK=64, dbuf gload_lds.
// ---------------------------------------------------------------------------
__global__ __launch_bounds__(256, 2)
void outgemm_kernel(const unsigned short* __restrict__ AP,
                    const unsigned short* __restrict__ BP,
                    float* __restrict__ out) {
    __shared__ __align__(16) unsigned short aL[2][4096];
    __shared__ __align__(16) unsigned short bL[2][8192];
    const int ox = blockIdx.x;
    const int my = blockIdx.y;
    const int tid  = threadIdx.x;
    const int lane = tid & 63;
    const int w    = tid >> 6;
    const int wr = (w & 1) * 32;
    const int wc = (w >> 1) * 64;
    const int l15  = lane & 15;
    const int kseg = (lane >> 4) * 16;

    f32x4 acc[2][4];
#pragma unroll
    for (int m = 0; m < 2; ++m)
#pragma unroll
        for (int n = 0; n < 4; ++n) acc[m][n] = (f32x4){0.f, 0.f, 0.f, 0.f};

    auto stage = [&](int buf, int kt) {
        const char* at = (const char*)AP + (size_t)(my * 16 + kt) * 8192;
        const char* bt = (const char*)BP + (size_t)(ox * 16 + kt) * 16384;
        gload16((char*)aL[buf] + tid * 16, at + tid * 16);
        gload16((char*)aL[buf] + 4096 + tid * 16, at + 4096 + tid * 16);
#pragma unroll
        for (int r = 0; r < 4; ++r)
            gload16((char*)bL[buf] + r * 4096 + tid * 16, bt + r * 4096 + tid * 16);
    };

    stage(0, 0);
    __syncthreads();
    int cur = 0;
    for (int kt = 0; kt < 16; ++kt) {
        if (kt < 15) stage(cur ^ 1, kt + 1);
#pragma unroll
        for (int ks = 0; ks < 2; ++ks) {
            bf16x8 aF[2], bF[4];
#pragma unroll
            for (int m = 0; m < 2; ++m) {
                int row = wr + m * 16 + l15;
                int off = (row * 128 + ks * 64 + kseg) ^ ((row & 7) << 4);
                aF[m] = __builtin_bit_cast(bf16x8, *(const uint4*)((const char*)aL[cur] + off));
            }
#pragma unroll
            for (int n = 0; n < 4; ++n) {
                int row = wc + n * 16 + l15;
                int off = (row * 128 + ks * 64 + kseg) ^ ((row & 7) << 4);
                bF[n] = __builtin_bit_cast(bf16x8, *(const uint4*)((const char*)bL[cur] + off));
            }
#pragma unroll
            for (int m = 0; m < 2; ++m)
#pragma unroll
                for (int n = 0; n < 4; ++n)
                    acc[m][n] = __builtin_amdgcn_mfma_f32_16x16x32_bf16(
                        aF[m], bF[n], acc[m][n], 0, 0, 0);
        }
        __syncthreads();
        cur ^= 1;
    }
#pragma unroll
    for (int m = 0; m < 2; ++m)
#pragma unroll
        for (int n = 0; n < 4; ++n)
#pragma unroll
            for (int r = 0; r < 4; ++r) {
                int row = my * 64 + wr + m * 16 + (lane >> 4) * 4 + r;
                int col = ox * 128 + wc + n * 16 + l15;
                out[(size_t)row * ND + col] = acc[m][n][r];
            }
}

// ---------------------------------------------------------------------------
extern "C" void kernel_launch(void* const* d_in, const int* in_sizes, int n_in,
                              void* d_out, int out_size, void* d_ws, size_t ws_size,
                              hipStream_t stream) {
    const float* query = (const float*)d_in[0];
    const float* key   = (const float*)d_in[1];
    const float* value = (const float*)d_in[2];
    const int*   pad   = (const int*)d_in[3];
    const float* q_w   = (const float*)d_in[4];
    const float* k_w   = (const float*)d_in[5];
    const float* v_w   = (const float*)d_in[6];
    const float* o_w   = (const float*)d_in[7];
    float* out = (float*)d_out;

    char* W = (char*)d_ws;
    float*          sums = (float*)W;                        // 48 KB
    unsigned short* kPhi = (unsigned short*)(W + 49152);     // 2 MB
    unsigned short* kPlo = (unsigned short*)(W + 2146304);   // 2 MB
    unsigned short* vP   = (unsigned short*)(W + 4243456);   // 2 MB
    unsigned short* BP   = (unsigned short*)(W + 6340608);   // 2 MB
    unsigned short* AP   = (unsigned short*)(W + 8437760);   // 8 MB

    // SUF lives in d_out scratch space: written by prep, read by attn,
    // fully overwritten by outgemm afterwards (stream-ordered).
    float* SUF = out;   // 16*16*4*64 f32 = 256 KB << 16 MB

    rowsum_kernel<<<3 * (NB * NL) / 4, 256, 0, stream>>>(query, key, value, sums);

    prep_kernel<<<656, 256, 0, stream>>>(k_w, v_w, o_w, sums, kPhi, kPlo, vP, BP, SUF);

    attn_kernel<<<512, 512, 0, stream>>>(q_w, pad, sums, kPhi, kPlo, vP, SUF, AP);

    dim3 gg(8, 64);
    outgemm_kernel<<<gg, 256, 0, stream>>>(AP, BP, out);
}

// Round 6
// 73.100 us; speedup vs baseline: 1.2369x; 1.2369x over previous
//
#include <hip/hip_runtime.h>
#include <hip/hip_bf16.h>

#define NB 4
#define NL 1024
#define NH 16
#define ND 1024
#define HD 64
#define FMIN_F32 (-3.4028234663852886e38f)
#define LOG2E 1.4426950408889634f

typedef __bf16 bf16x8 __attribute__((ext_vector_type(8)));
typedef float f32x4 __attribute__((ext_vector_type(4)));
typedef unsigned int u32;

static __device__ inline unsigned short f2bf(float f) {
    __hip_bfloat16 h = __float2bfloat16(f);
    return __builtin_bit_cast(unsigned short, h);
}

// split f32 into bf16 hi + bf16 lo (x ~= hi + lo, error ~2^-18 rel)
static __device__ inline void bfsplit(float x, unsigned short& hi, unsigned short& lo) {
    unsigned u = __builtin_bit_cast(unsigned, x);
    unsigned r = (u + 0x7FFFu + ((u >> 16) & 1u)) >> 16;
    hi = (unsigned short)r;
    float hf = __builtin_bit_cast(float, r << 16);
    lo = f2bf(x - hf);
}

// async global->LDS, 16B per lane. LDS dest = firstlane(lds)+lane*16.
static __device__ __forceinline__ void gload16(void* lds, const void* g) {
    __builtin_amdgcn_global_load_lds(
        (const __attribute__((address_space(1))) u32*)g,
        (__attribute__((address_space(3))) u32*)lds, 16, 0, 0);
}

// ---------------------------------------------------------------------------
// Kernel 1: row sums of query/key/value.
// ---------------------------------------------------------------------------
__global__ __launch_bounds__(256)
void rowsum_kernel(const float* __restrict__ q, const float* __restrict__ k,
                   const float* __restrict__ v, float* __restrict__ out) {
    int gw   = blockIdx.x * 4 + (threadIdx.x >> 6);
    int lane = threadIdx.x & 63;
    int tensor = gw >> 12;
    int row    = gw & 4095;
    const float* src = tensor == 0 ? q : (tensor == 1 ? k : v);
    const float* p = src + (size_t)row * ND;
    float s = 0.f;
#pragma unroll
    for (int t = 0; t < 4; ++t) {
        float4 x = *reinterpret_cast<const float4*>(p + t * 256 + lane * 4);
        s += (x.x + x.y) + (x.z + x.w);
    }
#pragma unroll
    for (int off = 32; off; off >>= 1) s += __shfl_xor(s, off);
    if (lane == 0) out[tensor * (NB * NL) + row] = s;
}

// ---------------------------------------------------------------------------
// Kernel 2: prep — pre-swizzled operand tiles + per-tile S sums.
//  blocks [0,256):   k_w -> kPhi/kPlo  [h][jt] 8KB tiles, (j_local, s)
//  blocks [256,512): v_w -> vP         [h][jt] 8KB tiles, (t, j_local) (transposed)
//                    + S[h][jt][b][t] = sum_{j in jt} vs_b[j]*V_h[j][t]  (jt>=1)
//  blocks [512,640): o_w -> BP         [ot][kt] 16KB tiles, (o, c) (transposed)
// ---------------------------------------------------------------------------
__global__ __launch_bounds__(256)
void prep_kernel(const float* __restrict__ k_w, const float* __restrict__ v_w,
                 const float* __restrict__ o_w, const float* __restrict__ sums,
                 unsigned short* __restrict__ kPhi, unsigned short* __restrict__ kPlo,
                 unsigned short* __restrict__ vP, unsigned short* __restrict__ BP,
                 float* __restrict__ S) {
    __shared__ float tile[64][132];
    __shared__ float vsL[256];
    const int tid = threadIdx.x;
    const int bx  = blockIdx.x;
    if (bx < 256) {
        const int h = bx >> 4, jt = bx & 15;
        char* hiT = (char*)kPhi + (size_t)(h * 16 + jt) * 8192;
        char* loT = (char*)kPlo + (size_t)(h * 16 + jt) * 8192;
        const int row = tid >> 2;
        const int s0  = (tid & 3) * 16;
        const float* src = k_w + ((size_t)(h * NL + jt * 64 + row)) * HD + s0;
#pragma unroll
        for (int t = 0; t < 4; ++t) {
            float4 x = reinterpret_cast<const float4*>(src)[t];
            unsigned short h0, h1, h2, h3, l0, l1, l2, l3;
            bfsplit(x.x, h0, l0); bfsplit(x.y, h1, l1);
            bfsplit(x.z, h2, l2); bfsplit(x.w, h3, l3);
            int off = (row * 128 + (s0 + 4 * t) * 2) ^ ((row & 7) << 4);
            *(uint2*)(hiT + off) = make_uint2((u32)h0 | ((u32)h1 << 16),
                                              (u32)h2 | ((u32)h3 << 16));
            *(uint2*)(loT + off) = make_uint2((u32)l0 | ((u32)l1 << 16),
                                              (u32)l2 | ((u32)l3 << 16));
        }
    } else if (bx < 512) {
        const int h = (bx - 256) >> 4, jt = (bx - 256) & 15;
#pragma unroll
        for (int t = 0; t < 4; ++t) {
            int id = tid + 256 * t;
            int j = id >> 4, t4 = (id & 15) * 4;
            *(float4*)&tile[j][t4] =
                *(const float4*)(v_w + ((size_t)(h * NL + jt * 64 + j)) * HD + t4);
        }
        // stage vsum slice for S
        vsL[tid] = sums[2 * NB * NL + (tid >> 6) * NL + jt * 64 + (tid & 63)];
        __syncthreads();
        char* vT_ = (char*)vP + (size_t)(h * 16 + jt) * 8192;
        const int trow = tid >> 2;
        const int jq   = (tid & 3) * 16;
#pragma unroll
        for (int q = 0; q < 4; ++q) {
            int j4 = jq + 4 * q;
            uint2 u;
            u.x = (u32)f2bf(tile[j4 + 0][trow]) | ((u32)f2bf(tile[j4 + 1][trow]) << 16);
            u.y = (u32)f2bf(tile[j4 + 2][trow]) | ((u32)f2bf(tile[j4 + 3][trow]) << 16);
            int off = (trow * 128 + j4 * 2) ^ ((trow & 7) << 4);
            *(uint2*)(vT_ + off) = u;
        }
        // S[h][jt][b][t] (only jt>=1 is ever read)
        if (jt >= 1) {
            const int b = tid >> 6, t = tid & 63;
            float a = 0.f;
#pragma unroll 16
            for (int j = 0; j < 64; ++j)
                a = fmaf(vsL[b * 64 + j], tile[j][t], a);
            S[(((size_t)h * 16 + jt) * 4 + b) * 64 + t] = a;
        }
    } else {
        const int bxo = bx - 512;
        const int ot = bxo >> 4, kt = bxo & 15;
#pragma unroll
        for (int t = 0; t < 8; ++t) {
            int id = tid + 256 * t;
            int c = id >> 5, o4 = (id & 31) * 4;
            *(float4*)&tile[c][o4] =
                *(const float4*)(o_w + ((size_t)(kt * 64 + c)) * ND + ot * 128 + o4);
        }
        __syncthreads();
        char* bT = (char*)BP + (size_t)(ot * 16 + kt) * 16384;
#pragma unroll
        for (int t = 0; t < 8; ++t) {
            int id = tid + 256 * t;
            int ol = id >> 4, c4 = (id & 15) * 4;
            uint2 u;
            u.x = (u32)f2bf(tile[c4 + 0][ol]) | ((u32)f2bf(tile[c4 + 1][ol]) << 16);
            u.y = (u32)f2bf(tile[c4 + 2][ol]) | ((u32)f2bf(tile[c4 + 3][ol]) << 16);
            int off = (ol * 128 + c4 * 2) ^ ((ol & 7) << 4);
            *(uint2*)(bT + off) = u;
        }
    }
}

// ---------------------------------------------------------------------------
// Kernel 3: fused attn with causal-tile skip.
// 512 threads (8 waves), TI=32, TJ=64. 1D grid 512 = (itile 32) x (h 16),
// remapped so block pairs (bx, bx+256) have complementary work (cut sums = 17).
// Processes jt in [0, cut); fully-masked suffix added from S in the epilogue.
// ---------------------------------------------------------------------------
__global__ __launch_bounds__(512, 4)
void attn_kernel(const float* __restrict__ q_w, const int* __restrict__ pad,
                 const float* __restrict__ sums,
                 const unsigned short* __restrict__ kPhi,
                 const unsigned short* __restrict__ kPlo,
                 const unsigned short* __restrict__ vP,
                 const float* __restrict__ S,
                 unsigned short* __restrict__ AP) {
    __shared__ __align__(16) unsigned short kHi[2][4096], kLo[2][4096], vTl[2][4096];
    __shared__ __align__(16) unsigned short qHi[2048], qLo[2048];
    __shared__ __align__(16) unsigned short wlds[8192];
    __shared__ __align__(16) float qs4[128];
    __shared__ __align__(16) float ks4[2][256];
    __shared__ __align__(16) float vs4[2][256];
    __shared__ __align__(16) int   pm4[2][256];

    const float* qsum = sums;
    const float* ksum = sums + NB * NL;
    const float* vsum = sums + 2 * NB * NL;

    const int wid = blockIdx.x;
    const int gq  = wid >> 4;
    const int h   = wid & 15;
    const int itp = (gq < 16) ? (2 * gq) : (63 - 2 * gq);  // work-balanced remap
    const int it0 = itp * 32;
    const int cut = (it0 >> 6) + 1;      // tiles [0,cut) have unmasked positions

    const int tid  = threadIdx.x;
    const int lane = tid & 63;
    const int w    = tid >> 6;
    const int l15  = lane & 15;
    const int kb   = (lane >> 4) * 16;

    // ---- stage q tile (f32 -> bf16 hi/lo, swizzled), once ----
    {
        int row = tid >> 4;
        int s4  = (tid & 15) * 4;
        float4 x = *(const float4*)(q_w + ((size_t)(h * NL + it0 + row)) * HD + s4);
        unsigned short h0, h1, h2, h3, l0, l1, l2, l3;
        bfsplit(x.x, h0, l0); bfsplit(x.y, h1, l1);
        bfsplit(x.z, h2, l2); bfsplit(x.w, h3, l3);
        int off = (row * 128 + s4 * 2) ^ ((row & 7) << 4);
        *(uint2*)((char*)qHi + off) = make_uint2((u32)h0 | ((u32)h1 << 16),
                                                 (u32)h2 | ((u32)h3 << 16));
        *(uint2*)((char*)qLo + off) = make_uint2((u32)l0 | ((u32)l1 << 16),
                                                 (u32)l2 | ((u32)l3 << 16));
    }
    if (tid < 128) {
        int b = tid >> 5, i = tid & 31;
        qs4[i * 4 + b] = qsum[b * NL + it0 + i];
    }

    auto stage = [&](int buf, int jt) {
        const size_t tb = (size_t)(h * 16 + jt) * 8192 + tid * 16;
        gload16((char*)kHi[buf] + tid * 16, (const char*)kPhi + tb);
        gload16((char*)kLo[buf] + tid * 16, (const char*)kPlo + tb);
        gload16((char*)vTl[buf] + tid * 16, (const char*)vP + tb);
        if (tid < 256) {
            int b = tid >> 6, jj = tid & 63;
            ks4[buf][jj * 4 + b] = ksum[b * NL + jt * 64 + jj] * LOG2E;
            vs4[buf][jj * 4 + b] = vsum[b * NL + jt * 64 + jj];
            pm4[buf][jj * 4 + b] = pad[b * NL + jt * 64 + jj];
        }
    };

    const int gmi = (w & 1) * 16;
    const int gnj = (w >> 1) * 16;
    const int pb  = w >> 1;
    const int pmh = (w & 1) * 16;

    f32x4 accP[4];
#pragma unroll
    for (int n = 0; n < 4; ++n) accP[n] = (f32x4){0.f, 0.f, 0.f, 0.f};

    stage(0, 0);
    __syncthreads();
    int cur = 0;

    for (int jt = 0; jt < cut; ++jt) {
        const int j0 = jt * 64;
        if (jt + 1 < cut) stage(cur ^ 1, jt + 1);

        // ---- G: one 16x16 fragment per wave, bf16x3 ----
        f32x4 g = (f32x4){0.f, 0.f, 0.f, 0.f};
#pragma unroll
        for (int ks = 0; ks < 2; ++ks) {
            const int arow = gmi + l15;
            const int brow = gnj + l15;
            const int aoff = (arow * 128 + ks * 64 + kb) ^ ((arow & 7) << 4);
            const int boff = (brow * 128 + ks * 64 + kb) ^ ((brow & 7) << 4);
            bf16x8 aHi = __builtin_bit_cast(bf16x8, *(const uint4*)((const char*)qHi + aoff));
            bf16x8 aLo = __builtin_bit_cast(bf16x8, *(const uint4*)((const char*)qLo + aoff));
            bf16x8 bHi = __builtin_bit_cast(bf16x8, *(const uint4*)((const char*)kHi[cur] + boff));
            bf16x8 bLo = __builtin_bit_cast(bf16x8, *(const uint4*)((const char*)kLo[cur] + boff));
            g = __builtin_amdgcn_mfma_f32_16x16x32_bf16(aHi, bHi, g, 0, 0, 0);
            g = __builtin_amdgcn_mfma_f32_16x16x32_bf16(aLo, bHi, g, 0, 0, 0);
            g = __builtin_amdgcn_mfma_f32_16x16x32_bf16(aHi, bLo, g, 0, 0, 0);
        }

        // ---- per-lane 4-batch softmax (exp2 domain) -> bf16 weights*vsum ----
        {
            const int j  = gnj + l15;
            const int jg = j0 + j;
            const float4 ksv = *(const float4*)&ks4[cur][j * 4];
            const float4 vsv = *(const float4*)&vs4[cur][j * 4];
            const int4   pmv = *(const int4*)&pm4[cur][j * 4];
#pragma unroll
            for (int r = 0; r < 4; ++r) {
                const int il = gmi + (lane >> 4) * 4 + r;
                const int ig = it0 + il;
                const float gv = g[r] * 0.25f;
                const float4 qsv = *(const float4*)&qs4[il * 4];
                const bool causal = jg > ig;
                const float sb0 = (causal || pmv.x) ? FMIN_F32 : qsv.x * ksv.x * gv;
                const float sb1 = (causal || pmv.y) ? FMIN_F32 : qsv.y * ksv.y * gv;
                const float sb2 = (causal || pmv.z) ? FMIN_F32 : qsv.z * ksv.z * gv;
                const float sb3 = (causal || pmv.w) ? FMIN_F32 : qsv.w * ksv.w * gv;
                const float mx = fmaxf(fmaxf(sb0, sb1), fmaxf(sb2, sb3));
                const float e0 = __builtin_amdgcn_exp2f(sb0 - mx);
                const float e1 = __builtin_amdgcn_exp2f(sb1 - mx);
                const float e2 = __builtin_amdgcn_exp2f(sb2 - mx);
                const float e3 = __builtin_amdgcn_exp2f(sb3 - mx);
                const float inv = __builtin_amdgcn_rcpf((e0 + e1) + (e2 + e3));
                const int off = (il * 128 + j * 2) ^ ((il & 7) << 4);
                *(unsigned short*)((char*)wlds + off)         = f2bf(e0 * inv * vsv.x);
                *(unsigned short*)((char*)wlds + 4096 + off)  = f2bf(e1 * inv * vsv.y);
                *(unsigned short*)((char*)wlds + 8192 + off)  = f2bf(e2 * inv * vsv.z);
                *(unsigned short*)((char*)wlds + 12288 + off) = f2bf(e3 * inv * vsv.w);
            }
        }
        __syncthreads();   // wlds ready; staging drained

        // ---- PV: wave (pb, pmh): 16 i-rows x 64 t for batch pb ----
#pragma unroll
        for (int ks = 0; ks < 2; ++ks) {
            const int arow = pmh + l15;
            const int aoff = pb * 4096 + ((arow * 128 + ks * 64 + kb) ^ ((arow & 7) << 4));
            bf16x8 aF = __builtin_bit_cast(bf16x8, *(const uint4*)((const char*)wlds + aoff));
#pragma unroll
            for (int n = 0; n < 4; ++n) {
                const int vrow = n * 16 + l15;
                const int voff = (vrow * 128 + ks * 64 + kb) ^ ((vrow & 7) << 4);
                bf16x8 bF = __builtin_bit_cast(bf16x8, *(const uint4*)((const char*)vTl[cur] + voff));
                accP[n] = __builtin_amdgcn_mfma_f32_16x16x32_bf16(aF, bF, accP[n], 0, 0, 0);
            }
        }
        __syncthreads();   // PV done reading wlds/vTl before next overwrite
        cur ^= 1;
    }

    // ---- add fully-masked causal suffix: 0.25 * sum_{jt>=cut} S[h][jt][pb][t] ----
    if (cut < 16) {
        float sv[4] = {0.f, 0.f, 0.f, 0.f};
        for (int jt = cut; jt < 16; ++jt) {
            const float* sp = S + (((size_t)h * 16 + jt) * 4 + pb) * 64;
#pragma unroll
            for (int n = 0; n < 4; ++n) sv[n] += sp[n * 16 + l15];
        }
#pragma unroll
        for (int n = 0; n < 4; ++n) {
            const float s4v = 0.25f * sv[n];
#pragma unroll
            for (int r = 0; r < 4; ++r) accP[n][r] += s4v;
        }
    }

    // ---- store AP tiles (pre-swizzled out-GEMM A layout, bf16) ----
    {
        const int ib = (it0 + pmh) >> 4;
        char* tbase = (char*)AP + (size_t)((pb * 16 + h) * 16) * 8192;
#pragma unroll
        for (int n = 0; n < 4; ++n)
#pragma unroll
            for (int r = 0; r < 4; ++r) {
                int kt = (lane >> 4) * 4 + r;
                int tt = n * 16 + l15;
                int off = (ib * 128 + tt * 2) ^ ((ib & 7) << 4);
                *(unsigned short*)(tbase + (size_t)kt * 8192 + off) = f2bf(accP[n][r]);
            }
    }
}

// ---------------------------------------------------------------------------
// Kernel 4: out(4096x1024) = AP(4096x1024 bf16) @ BP(1024x1024 bf16 [o][c]^T).
// 64x128 tiles, grid (8, 64) = 512 blocks, 256 threads, BK=64, dbuf gload_lds.
// ---------------------------------------------------------------------------
__global__ __launch_bounds__(256, 2)
void outgemm_kernel(const unsigned short* __restrict__ AP,
                    const unsigned short* __restrict__ BP,
                    float* __restrict__ out) {
    __shared__ __align__(16) unsigned short aL[2][4096];
    __shared__ __align__(16) unsigned short bL[2][8192];
    const int ox = blockIdx.x;
    const int my = blockIdx.y;
    const int tid  = threadIdx.x;
    const int lane = tid & 63;
    const int w    = tid >> 6;
    const int wr = (w & 1) * 32;
    const int wc = (w >> 1) * 64;
    const int l15  = lane & 15;
    const int kseg = (lane >> 4) * 16;

    f32x4 acc[2][4];
#pragma unroll
    for (int m = 0; m < 2; ++m)
#pragma unroll
        for (int n = 0; n < 4; ++n) acc[m][n] = (f32x4){0.f, 0.f, 0.f, 0.f};

    auto stage = [&](int buf, int kt) {
        const char* at = (const char*)AP + (size_t)(my * 16 + kt) * 8192;
        const char* bt = (const char*)BP + (size_t)(ox * 16 + kt) * 16384;
        gload16((char*)aL[buf] + tid * 16, at + tid * 16);
        gload16((char*)aL[buf] + 4096 + tid * 16, at + 4096 + tid * 16);
#pragma unroll
        for (int r = 0; r < 4; ++r)
            gload16((char*)bL[buf] + r * 4096 + tid * 16, bt + r * 4096 + tid * 16);
    };

    stage(0, 0);
    __syncthreads();
    int cur = 0;
    for (int kt = 0; kt < 16; ++kt) {
        if (kt < 15) stage(cur ^ 1, kt + 1);
#pragma unroll
        for (int ks = 0; ks < 2; ++ks) {
            bf16x8 aF[2], bF[4];
#pragma unroll
            for (int m = 0; m < 2; ++m) {
                int row = wr + m * 16 + l15;
                int off = (row * 128 + ks * 64 + kseg) ^ ((row & 7) << 4);
                aF[m] = __builtin_bit_cast(bf16x8, *(const uint4*)((const char*)aL[cur] + off));
            }
#pragma unroll
            for (int n = 0; n < 4; ++n) {
                int row = wc + n * 16 + l15;
                int off = (row * 128 + ks * 64 + kseg) ^ ((row & 7) << 4);
                bF[n] = __builtin_bit_cast(bf16x8, *(const uint4*)((const char*)bL[cur] + off));
            }
#pragma unroll
            for (int m = 0; m < 2; ++m)
#pragma unroll
                for (int n = 0; n < 4; ++n)
                    acc[m][n] = __builtin_amdgcn_mfma_f32_16x16x32_bf16(
                        aF[m], bF[n], acc[m][n], 0, 0, 0);
        }
        __syncthreads();
        cur ^= 1;
    }
#pragma unroll
    for (int m = 0; m < 2; ++m)
#pragma unroll
        for (int n = 0; n < 4; ++n)
#pragma unroll
            for (int r = 0; r < 4; ++r) {
                int row = my * 64 + wr + m * 16 + (lane >> 4) * 4 + r;
                int col = ox * 128 + wc + n * 16 + l15;
                out[(size_t)row * ND + col] = acc[m][n][r];
            }
}

// ---------------------------------------------------------------------------
extern "C" void kernel_launch(void* const* d_in, const int* in_sizes, int n_in,
                              void* d_out, int out_size, void* d_ws, size_t ws_size,
                              hipStream_t stream) {
    const float* query = (const float*)d_in[0];
    const float* key   = (const float*)d_in[1];
    const float* value = (const float*)d_in[2];
    const int*   pad   = (const int*)d_in[3];
    const float* q_w   = (const float*)d_in[4];
    const float* k_w   = (const float*)d_in[5];
    const float* v_w   = (const float*)d_in[6];
    const float* o_w   = (const float*)d_in[7];
    float* out = (float*)d_out;

    char* W = (char*)d_ws;
    float*          sums = (float*)W;                        // 48 KB
    unsigned short* kPhi = (unsigned short*)(W + 49152);     // 2 MB
    unsigned short* kPlo = (unsigned short*)(W + 2146304);   // 2 MB
    unsigned short* vP   = (unsigned short*)(W + 4243456);   // 2 MB
    unsigned short* BP   = (unsigned short*)(W + 6340608);   // 2 MB
    unsigned short* AP   = (unsigned short*)(W + 8437760);   // 8 MB

    // S (per-tile masked PV sums) lives in d_out scratch: written by prep,
    // read by attn, fully overwritten by outgemm afterwards (stream-ordered).
    float* S = out;   // 16*16*4*64 f32 = 256 KB << 16 MB

    rowsum_kernel<<<3 * (NB * NL) / 4, 256, 0, stream>>>(query, key, value, sums);

    prep_kernel<<<640, 256, 0, stream>>>(k_w, v_w, o_w, sums, kPhi, kPlo, vP, BP, S);

    attn_kernel<<<512, 512, 0, stream>>>(q_w, pad, sums, kPhi, kPlo, vP, S, AP);

    dim3 gg(8, 64);
    outgemm_kernel<<<gg, 256, 0, stream>>>(AP, BP, out);
}

// Round 7
// 71.931 us; speedup vs baseline: 1.2570x; 1.0163x over previous
//
#include <hip/hip_runtime.h>
#include <hip/hip_bf16.h>

#define NB 4
#define NL 1024
#define NH 16
#define ND 1024
#define HD 64
#define FMIN_F32 (-3.4028234663852886e38f)
#define LOG2E 1.4426950408889634f

typedef __bf16 bf16x8 __attribute__((ext_vector_type(8)));
typedef float f32x4 __attribute__((ext_vector_type(4)));
typedef unsigned int u32;

static __device__ inline unsigned short f2bf(float f) {
    __hip_bfloat16 h = __float2bfloat16(f);
    return __builtin_bit_cast(unsigned short, h);
}

// split f32 into bf16 hi + bf16 lo (x ~= hi + lo, error ~2^-18 rel)
static __device__ inline void bfsplit(float x, unsigned short& hi, unsigned short& lo) {
    unsigned u = __builtin_bit_cast(unsigned, x);
    unsigned r = (u + 0x7FFFu + ((u >> 16) & 1u)) >> 16;
    hi = (unsigned short)r;
    float hf = __builtin_bit_cast(float, r << 16);
    lo = f2bf(x - hf);
}

// async global->LDS, 16B per lane. LDS dest = firstlane(lds)+lane*16.
static __device__ __forceinline__ void gload16(void* lds, const void* g) {
    __builtin_amdgcn_global_load_lds(
        (const __attribute__((address_space(1))) u32*)g,
        (__attribute__((address_space(3))) u32*)lds, 16, 0, 0);
}

// ---------------------------------------------------------------------------
// Kernel 1: row sums of query/key/value.
// ---------------------------------------------------------------------------
__global__ __launch_bounds__(256)
void rowsum_kernel(const float* __restrict__ q, const float* __restrict__ k,
                   const float* __restrict__ v, float* __restrict__ out) {
    int gw   = blockIdx.x * 4 + (threadIdx.x >> 6);
    int lane = threadIdx.x & 63;
    int tensor = gw >> 12;
    int row    = gw & 4095;
    const float* src = tensor == 0 ? q : (tensor == 1 ? k : v);
    const float* p = src + (size_t)row * ND;
    float s = 0.f;
#pragma unroll
    for (int t = 0; t < 4; ++t) {
        float4 x = *reinterpret_cast<const float4*>(p + t * 256 + lane * 4);
        s += (x.x + x.y) + (x.z + x.w);
    }
#pragma unroll
    for (int off = 32; off; off >>= 1) s += __shfl_xor(s, off);
    if (lane == 0) out[tensor * (NB * NL) + row] = s;
}

// ---------------------------------------------------------------------------
// Kernel 2: prep — pre-swizzled operand tiles + per-tile S sums.
//  blocks [0,256):   k_w -> kPhi/kPlo  [h][jt] 8KB tiles, (j_local, s)
//  blocks [256,512): v_w -> vP         [h][jt] 8KB tiles, (t, j_local) (transposed)
//                    + S[h][jt][b][t] = sum_{j in jt} vs_b[j]*V_h[j][t]  (jt>=1)
//  blocks [512,640): o_w -> BP         [ot][kt] 16KB tiles, (o, c) (transposed)
// ---------------------------------------------------------------------------
__global__ __launch_bounds__(256)
void prep_kernel(const float* __restrict__ k_w, const float* __restrict__ v_w,
                 const float* __restrict__ o_w, const float* __restrict__ sums,
                 unsigned short* __restrict__ kPhi, unsigned short* __restrict__ kPlo,
                 unsigned short* __restrict__ vP, unsigned short* __restrict__ BP,
                 float* __restrict__ S) {
    __shared__ float tile[64][132];
    __shared__ float vsL[256];
    const int tid = threadIdx.x;
    const int bx  = blockIdx.x;
    if (bx < 256) {
        const int h = bx >> 4, jt = bx & 15;
        char* hiT = (char*)kPhi + (size_t)(h * 16 + jt) * 8192;
        char* loT = (char*)kPlo + (size_t)(h * 16 + jt) * 8192;
        const int row = tid >> 2;
        const int s0  = (tid & 3) * 16;
        const float* src = k_w + ((size_t)(h * NL + jt * 64 + row)) * HD + s0;
#pragma unroll
        for (int t = 0; t < 4; ++t) {
            float4 x = reinterpret_cast<const float4*>(src)[t];
            unsigned short h0, h1, h2, h3, l0, l1, l2, l3;
            bfsplit(x.x, h0, l0); bfsplit(x.y, h1, l1);
            bfsplit(x.z, h2, l2); bfsplit(x.w, h3, l3);
            int off = (row * 128 + (s0 + 4 * t) * 2) ^ ((row & 7) << 4);
            *(uint2*)(hiT + off) = make_uint2((u32)h0 | ((u32)h1 << 16),
                                              (u32)h2 | ((u32)h3 << 16));
            *(uint2*)(loT + off) = make_uint2((u32)l0 | ((u32)l1 << 16),
                                              (u32)l2 | ((u32)l3 << 16));
        }
    } else if (bx < 512) {
        const int h = (bx - 256) >> 4, jt = (bx - 256) & 15;
#pragma unroll
        for (int t = 0; t < 4; ++t) {
            int id = tid + 256 * t;
            int j = id >> 4, t4 = (id & 15) * 4;
            *(float4*)&tile[j][t4] =
                *(const float4*)(v_w + ((size_t)(h * NL + jt * 64 + j)) * HD + t4);
        }
        // stage vsum slice for S
        vsL[tid] = sums[2 * NB * NL + (tid >> 6) * NL + jt * 64 + (tid & 63)];
        __syncthreads();
        char* vT_ = (char*)vP + (size_t)(h * 16 + jt) * 8192;
        const int trow = tid >> 2;
        const int jq   = (tid & 3) * 16;
#pragma unroll
        for (int q = 0; q < 4; ++q) {
            int j4 = jq + 4 * q;
            uint2 u;
            u.x = (u32)f2bf(tile[j4 + 0][trow]) | ((u32)f2bf(tile[j4 + 1][trow]) << 16);
            u.y = (u32)f2bf(tile[j4 + 2][trow]) | ((u32)f2bf(tile[j4 + 3][trow]) << 16);
            int off = (trow * 128 + j4 * 2) ^ ((trow & 7) << 4);
            *(uint2*)(vT_ + off) = u;
        }
        // S[h][jt][b][t] (only jt>=1 is ever read)
        if (jt >= 1) {
            const int b = tid >> 6, t = tid & 63;
            float a = 0.f;
#pragma unroll 16
            for (int j = 0; j < 64; ++j)
                a = fmaf(vsL[b * 64 + j], tile[j][t], a);
            S[(((size_t)h * 16 + jt) * 4 + b) * 64 + t] = a;
        }
    } else {
        const int bxo = bx - 512;
        const int ot = bxo >> 4, kt = bxo & 15;
#pragma unroll
        for (int t = 0; t < 8; ++t) {
            int id = tid + 256 * t;
            int c = id >> 5, o4 = (id & 31) * 4;
            *(float4*)&tile[c][o4] =
                *(const float4*)(o_w + ((size_t)(kt * 64 + c)) * ND + ot * 128 + o4);
        }
        __syncthreads();
        char* bT = (char*)BP + (size_t)(ot * 16 + kt) * 16384;
#pragma unroll
        for (int t = 0; t < 8; ++t) {
            int id = tid + 256 * t;
            int ol = id >> 4, c4 = (id & 15) * 4;
            uint2 u;
            u.x = (u32)f2bf(tile[c4 + 0][ol]) | ((u32)f2bf(tile[c4 + 1][ol]) << 16);
            u.y = (u32)f2bf(tile[c4 + 2][ol]) | ((u32)f2bf(tile[c4 + 3][ol]) << 16);
            int off = (ol * 128 + c4 * 2) ^ ((ol & 7) << 4);
            *(uint2*)(bT + off) = u;
        }
    }
}

// ---------------------------------------------------------------------------
// Kernel 3: fused attn with causal-tile skip.
// 512 threads (8 waves), TI=32, TJ=64. 1D grid 512 = (itile 32) x (h 16),
// remapped so block pairs have complementary work (cut sums = 17).
// Barrier A (pre-PV) is lgkm-only: jt+1 gload_lds stages stay in flight
// through PV and are drained at the full tile-end barrier.
// ---------------------------------------------------------------------------
__global__ __launch_bounds__(512, 4)
void attn_kernel(const float* __restrict__ q_w, const int* __restrict__ pad,
                 const float* __restrict__ sums,
                 const unsigned short* __restrict__ kPhi,
                 const unsigned short* __restrict__ kPlo,
                 const unsigned short* __restrict__ vP,
                 const float* __restrict__ S,
                 unsigned short* __restrict__ AP) {
    __shared__ __align__(16) unsigned short kHi[2][4096], kLo[2][4096], vTl[2][4096];
    __shared__ __align__(16) unsigned short qHi[2048], qLo[2048];
    __shared__ __align__(16) unsigned short wlds[8192];
    __shared__ __align__(16) float qs4[128];
    __shared__ __align__(16) float ks4[2][256];
    __shared__ __align__(16) float vs4[2][256];
    __shared__ __align__(16) int   pm4[2][256];

    const float* qsum = sums;
    const float* ksum = sums + NB * NL;
    const float* vsum = sums + 2 * NB * NL;

    const int wid = blockIdx.x;
    const int gq  = wid >> 4;
    const int h   = wid & 15;
    const int itp = (gq < 16) ? (2 * gq) : (63 - 2 * gq);  // work-balanced remap
    const int it0 = itp * 32;
    const int cut = (it0 >> 6) + 1;      // tiles [0,cut) have unmasked positions

    const int tid  = threadIdx.x;
    const int lane = tid & 63;
    const int w    = tid >> 6;
    const int l15  = lane & 15;
    const int kb   = (lane >> 4) * 16;

    // ---- stage q tile (f32 -> bf16 hi/lo, swizzled), once ----
    {
        int row = tid >> 4;
        int s4  = (tid & 15) * 4;
        float4 x = *(const float4*)(q_w + ((size_t)(h * NL + it0 + row)) * HD + s4);
        unsigned short h0, h1, h2, h3, l0, l1, l2, l3;
        bfsplit(x.x, h0, l0); bfsplit(x.y, h1, l1);
        bfsplit(x.z, h2, l2); bfsplit(x.w, h3, l3);
        int off = (row * 128 + s4 * 2) ^ ((row & 7) << 4);
        *(uint2*)((char*)qHi + off) = make_uint2((u32)h0 | ((u32)h1 << 16),
                                                 (u32)h2 | ((u32)h3 << 16));
        *(uint2*)((char*)qLo + off) = make_uint2((u32)l0 | ((u32)l1 << 16),
                                                 (u32)l2 | ((u32)l3 << 16));
    }
    if (tid < 128) {
        int b = tid >> 5, i = tid & 31;
        qs4[i * 4 + b] = qsum[b * NL + it0 + i];
    }

    auto stage = [&](int buf, int jt) {
        const size_t tb = (size_t)(h * 16 + jt) * 8192 + tid * 16;
        gload16((char*)kHi[buf] + tid * 16, (const char*)kPhi + tb);
        gload16((char*)kLo[buf] + tid * 16, (const char*)kPlo + tb);
        gload16((char*)vTl[buf] + tid * 16, (const char*)vP + tb);
        if (tid < 256) {
            int b = tid >> 6, jj = tid & 63;
            ks4[buf][jj * 4 + b] = ksum[b * NL + jt * 64 + jj] * LOG2E;
            vs4[buf][jj * 4 + b] = vsum[b * NL + jt * 64 + jj];
            pm4[buf][jj * 4 + b] = pad[b * NL + jt * 64 + jj];
        }
    };

    const int gmi = (w & 1) * 16;
    const int gnj = (w >> 1) * 16;
    const int pb  = w >> 1;
    const int pmh = (w & 1) * 16;

    f32x4 accP[4];
#pragma unroll
    for (int n = 0; n < 4; ++n) accP[n] = (f32x4){0.f, 0.f, 0.f, 0.f};

    stage(0, 0);
    __syncthreads();
    int cur = 0;

    for (int jt = 0; jt < cut; ++jt) {
        const int j0 = jt * 64;
        if (jt + 1 < cut) stage(cur ^ 1, jt + 1);

        // ---- G: one 16x16 fragment per wave, bf16x3 ----
        f32x4 g = (f32x4){0.f, 0.f, 0.f, 0.f};
#pragma unroll
        for (int ks = 0; ks < 2; ++ks) {
            const int arow = gmi + l15;
            const int brow = gnj + l15;
            const int aoff = (arow * 128 + ks * 64 + kb) ^ ((arow & 7) << 4);
            const int boff = (brow * 128 + ks * 64 + kb) ^ ((brow & 7) << 4);
            bf16x8 aHi = __builtin_bit_cast(bf16x8, *(const uint4*)((const char*)qHi + aoff));
            bf16x8 aLo = __builtin_bit_cast(bf16x8, *(const uint4*)((const char*)qLo + aoff));
            bf16x8 bHi = __builtin_bit_cast(bf16x8, *(const uint4*)((const char*)kHi[cur] + boff));
            bf16x8 bLo = __builtin_bit_cast(bf16x8, *(const uint4*)((const char*)kLo[cur] + boff));
            g = __builtin_amdgcn_mfma_f32_16x16x32_bf16(aHi, bHi, g, 0, 0, 0);
            g = __builtin_amdgcn_mfma_f32_16x16x32_bf16(aLo, bHi, g, 0, 0, 0);
            g = __builtin_amdgcn_mfma_f32_16x16x32_bf16(aHi, bLo, g, 0, 0, 0);
        }

        // ---- per-lane 4-batch softmax (exp2 domain) -> bf16 weights*vsum ----
        {
            const int j  = gnj + l15;
            const int jg = j0 + j;
            const float4 ksv = *(const float4*)&ks4[cur][j * 4];
            const float4 vsv = *(const float4*)&vs4[cur][j * 4];
            const int4   pmv = *(const int4*)&pm4[cur][j * 4];
#pragma unroll
            for (int r = 0; r < 4; ++r) {
                const int il = gmi + (lane >> 4) * 4 + r;
                const int ig = it0 + il;
                const float gv = g[r] * 0.25f;
                const float4 qsv = *(const float4*)&qs4[il * 4];
                const bool causal = jg > ig;
                const float sb0 = (causal || pmv.x) ? FMIN_F32 : qsv.x * ksv.x * gv;
                const float sb1 = (causal || pmv.y) ? FMIN_F32 : qsv.y * ksv.y * gv;
                const float sb2 = (causal || pmv.z) ? FMIN_F32 : qsv.z * ksv.z * gv;
                const float sb3 = (causal || pmv.w) ? FMIN_F32 : qsv.w * ksv.w * gv;
                const float mx = fmaxf(fmaxf(sb0, sb1), fmaxf(sb2, sb3));
                const float e0 = __builtin_amdgcn_exp2f(sb0 - mx);
                const float e1 = __builtin_amdgcn_exp2f(sb1 - mx);
                const float e2 = __builtin_amdgcn_exp2f(sb2 - mx);
                const float e3 = __builtin_amdgcn_exp2f(sb3 - mx);
                const float inv = __builtin_amdgcn_rcpf((e0 + e1) + (e2 + e3));
                const int off = (il * 128 + j * 2) ^ ((il & 7) << 4);
                *(unsigned short*)((char*)wlds + off)         = f2bf(e0 * inv * vsv.x);
                *(unsigned short*)((char*)wlds + 4096 + off)  = f2bf(e1 * inv * vsv.y);
                *(unsigned short*)((char*)wlds + 8192 + off)  = f2bf(e2 * inv * vsv.z);
                *(unsigned short*)((char*)wlds + 12288 + off) = f2bf(e3 * inv * vsv.w);
            }
        }
        // ---- barrier A: wlds visible; do NOT drain in-flight jt+1 stages ----
        asm volatile("s_waitcnt lgkmcnt(0)" ::: "memory");
        __builtin_amdgcn_s_barrier();
        __builtin_amdgcn_sched_barrier(0);

        // ---- PV: wave (pb, pmh): 16 i-rows x 64 t for batch pb ----
#pragma unroll
        for (int ks = 0; ks < 2; ++ks) {
            const int arow = pmh + l15;
            const int aoff = pb * 4096 + ((arow * 128 + ks * 64 + kb) ^ ((arow & 7) << 4));
            bf16x8 aF = __builtin_bit_cast(bf16x8, *(const uint4*)((const char*)wlds + aoff));
#pragma unroll
            for (int n = 0; n < 4; ++n) {
                const int vrow = n * 16 + l15;
                const int voff = (vrow * 128 + ks * 64 + kb) ^ ((vrow & 7) << 4);
                bf16x8 bF = __builtin_bit_cast(bf16x8, *(const uint4*)((const char*)vTl[cur] + voff));
                accP[n] = __builtin_amdgcn_mfma_f32_16x16x32_bf16(aF, bF, accP[n], 0, 0, 0);
            }
        }
        __syncthreads();   // full drain: stages landed, PV reads done
        cur ^= 1;
    }

    // ---- add fully-masked causal suffix: 0.25 * sum_{jt>=cut} S[h][jt][pb][t] ----
    if (cut < 16) {
        float sv[4] = {0.f, 0.f, 0.f, 0.f};
        for (int jt = cut; jt < 16; ++jt) {
            const float* sp = S + (((size_t)h * 16 + jt) * 4 + pb) * 64;
#pragma unroll
            for (int n = 0; n < 4; ++n) sv[n] += sp[n * 16 + l15];
        }
#pragma unroll
        for (int n = 0; n < 4; ++n) {
            const float s4v = 0.25f * sv[n];
#pragma unroll
            for (int r = 0; r < 4; ++r) accP[n][r] += s4v;
        }
    }

    // ---- store AP tiles (pre-swizzled out-GEMM A layout, bf16) ----
    {
        const int ib = (it0 + pmh) >> 4;
        char* tbase = (char*)AP + (size_t)((pb * 16 + h) * 16) * 8192;
#pragma unroll
        for (int n = 0; n < 4; ++n)
#pragma unroll
            for (int r = 0; r < 4; ++r) {
                int kt = (lane >> 4) * 4 + r;
                int tt = n * 16 + l15;
                int off = (ib * 128 + tt * 2) ^ ((ib & 7) << 4);
                *(unsigned short*)(tbase + (size_t)kt * 8192 + off) = f2bf(accP[n][r]);
            }
    }
}

// ---------------------------------------------------------------------------
// Kernel 4: out(4096x1024) = AP(4096x1024 bf16) @ BP(1024x1024 bf16 [o][c]^T).
// 64x128 tiles, grid (8, 64) = 512 blocks, 256 threads, BK=64.
// 2-phase schedule: issue stage(kt+1), compute(kt), ONE barrier (drain +
// read-protect) — loads overlap the 16 MFMAs instead of stalling before them.
// ---------------------------------------------------------------------------
__global__ __launch_bounds__(256, 2)
void outgemm_kernel(const unsigned short* __restrict__ AP,
                    const unsigned short* __restrict__ BP,
                    float* __restrict__ out) {
    __shared__ __align__(16) unsigned short aL[2][4096];
    __shared__ __align__(16) unsigned short bL[2][8192];
    const int ox = blockIdx.x;
    const int my = blockIdx.y;
    const int tid  = threadIdx.x;
    const int lane = tid & 63;
    const int w    = tid >> 6;
    const int wr = (w & 1) * 32;
    const int wc = (w >> 1) * 64;
    const int l15  = lane & 15;
    const int kseg = (lane >> 4) * 16;

    f32x4 acc[2][4];
#pragma unroll
    for (int m = 0; m < 2; ++m)
#pragma unroll
        for (int n = 0; n < 4; ++n) acc[m][n] = (f32x4){0.f, 0.f, 0.f, 0.f};

    auto stage = [&](int buf, int kt) {
        const char* at = (const char*)AP + (size_t)(my * 16 + kt) * 8192;
        const char* bt = (const char*)BP + (size_t)(ox * 16 + kt) * 16384;
        gload16((char*)aL[buf] + tid * 16, at + tid * 16);
        gload16((char*)aL[buf] + 4096 + tid * 16, at + 4096 + tid * 16);
#pragma unroll
        for (int r = 0; r < 4; ++r)
            gload16((char*)bL[buf] + r * 4096 + tid * 16, bt + r * 4096 + tid * 16);
    };

    stage(0, 0);
    __syncthreads();
    int cur = 0;
    for (int kt = 0; kt < 16; ++kt) {
        if (kt < 15) stage(cur ^ 1, kt + 1);   // issue BEFORE compute
#pragma unroll
        for (int ks = 0; ks < 2; ++ks) {
            bf16x8 aF[2], bF[4];
#pragma unroll
            for (int m = 0; m < 2; ++m) {
                int row = wr + m * 16 + l15;
                int off = (row * 128 + ks * 64 + kseg) ^ ((row & 7) << 4);
                aF[m] = __builtin_bit_cast(bf16x8, *(const uint4*)((const char*)aL[cur] + off));
            }
#pragma unroll
            for (int n = 0; n < 4; ++n) {
                int row = wc + n * 16 + l15;
                int off = (row * 128 + ks * 64 + kseg) ^ ((row & 7) << 4);
                bF[n] = __builtin_bit_cast(bf16x8, *(const uint4*)((const char*)bL[cur] + off));
            }
#pragma unroll
            for (int m = 0; m < 2; ++m)
#pragma unroll
                for (int n = 0; n < 4; ++n)
                    acc[m][n] = __builtin_amdgcn_mfma_f32_16x16x32_bf16(
                        aF[m], bF[n], acc[m][n], 0, 0, 0);
        }
        __syncthreads();   // drain stages + protect cur for overwrite next iter
        cur ^= 1;
    }
#pragma unroll
    for (int m = 0; m < 2; ++m)
#pragma unroll
        for (int n = 0; n < 4; ++n)
#pragma unroll
            for (int r = 0; r < 4; ++r) {
                int row = my * 64 + wr + m * 16 + (lane >> 4) * 4 + r;
                int col = ox * 128 + wc + n * 16 + l15;
                out[(size_t)row * ND + col] = acc[m][n][r];
            }
}

// ---------------------------------------------------------------------------
extern "C" void kernel_launch(void* const* d_in, const int* in_sizes, int n_in,
                              void* d_out, int out_size, void* d_ws, size_t ws_size,
                              hipStream_t stream) {
    const float* query = (const float*)d_in[0];
    const float* key   = (const float*)d_in[1];
    const float* value = (const float*)d_in[2];
    const int*   pad   = (const int*)d_in[3];
    const float* q_w   = (const float*)d_in[4];
    const float* k_w   = (const float*)d_in[5];
    const float* v_w   = (const float*)d_in[6];
    const float* o_w   = (const float*)d_in[7];
    float* out = (float*)d_out;

    char* W = (char*)d_ws;
    float*          sums = (float*)W;                        // 48 KB
    unsigned short* kPhi = (unsigned short*)(W + 49152);     // 2 MB
    unsigned short* kPlo = (unsigned short*)(W + 2146304);   // 2 MB
    unsigned short* vP   = (unsigned short*)(W + 4243456);   // 2 MB
    unsigned short* BP   = (unsigned short*)(W + 6340608);   // 2 MB
    unsigned short* AP   = (unsigned short*)(W + 8437760);   // 8 MB

    // S (per-tile masked PV sums) lives in d_out scratch: written by prep,
    // read by attn, fully overwritten by outgemm afterwards (stream-ordered).
    float* S = out;   // 16*16*4*64 f32 = 256 KB << 16 MB

    rowsum_kernel<<<3 * (NB * NL) / 4, 256, 0, stream>>>(query, key, value, sums);

    prep_kernel<<<640, 256, 0, stream>>>(k_w, v_w, o_w, sums, kPhi, kPlo, vP, BP, S);

    attn_kernel<<<512, 512, 0, stream>>>(q_w, pad, sums, kPhi, kPlo, vP, S, AP);

    dim3 gg(8, 64);
    outgemm_kernel<<<gg, 256, 0, stream>>>(AP, BP, out);
}

// Round 8
// 69.190 us; speedup vs baseline: 1.3068x; 1.0396x over previous
//
#include <hip/hip_runtime.h>
#include <hip/hip_bf16.h>

#define NB 4
#define NL 1024
#define NH 16
#define ND 1024
#define HD 64
#define FMIN_F32 (-3.4028234663852886e38f)
#define LOG2E 1.4426950408889634f

typedef __bf16 bf16x8 __attribute__((ext_vector_type(8)));
typedef float f32x4 __attribute__((ext_vector_type(4)));
typedef unsigned int u32;

static __device__ inline unsigned short f2bf(float f) {
    __hip_bfloat16 h = __float2bfloat16(f);
    return __builtin_bit_cast(unsigned short, h);
}

// split f32 into bf16 hi + bf16 lo (x ~= hi + lo, error ~2^-18 rel)
static __device__ inline void bfsplit(float x, unsigned short& hi, unsigned short& lo) {
    unsigned u = __builtin_bit_cast(unsigned, x);
    unsigned r = (u + 0x7FFFu + ((u >> 16) & 1u)) >> 16;
    hi = (unsigned short)r;
    float hf = __builtin_bit_cast(float, r << 16);
    lo = f2bf(x - hf);
}

// async global->LDS, 16B per lane. LDS dest = firstlane(lds)+lane*16.
static __device__ __forceinline__ void gload16(void* lds, const void* g) {
    __builtin_amdgcn_global_load_lds(
        (const __attribute__((address_space(1))) u32*)g,
        (__attribute__((address_space(3))) u32*)lds, 16, 0, 0);
}

// ---------------------------------------------------------------------------
// Kernel 1: row sums of query/key/value.
// ---------------------------------------------------------------------------
__global__ __launch_bounds__(256)
void rowsum_kernel(const float* __restrict__ q, const float* __restrict__ k,
                   const float* __restrict__ v, float* __restrict__ out) {
    int gw   = blockIdx.x * 4 + (threadIdx.x >> 6);
    int lane = threadIdx.x & 63;
    int tensor = gw >> 12;
    int row    = gw & 4095;
    const float* src = tensor == 0 ? q : (tensor == 1 ? k : v);
    const float* p = src + (size_t)row * ND;
    float s = 0.f;
#pragma unroll
    for (int t = 0; t < 4; ++t) {
        float4 x = *reinterpret_cast<const float4*>(p + t * 256 + lane * 4);
        s += (x.x + x.y) + (x.z + x.w);
    }
#pragma unroll
    for (int off = 32; off; off >>= 1) s += __shfl_xor(s, off);
    if (lane == 0) out[tensor * (NB * NL) + row] = s;
}

// ---------------------------------------------------------------------------
// Kernel 2: prep — pre-swizzled operand tiles + per-tile S sums.
// ---------------------------------------------------------------------------
__global__ __launch_bounds__(256)
void prep_kernel(const float* __restrict__ k_w, const float* __restrict__ v_w,
                 const float* __restrict__ o_w, const float* __restrict__ sums,
                 unsigned short* __restrict__ kPhi, unsigned short* __restrict__ kPlo,
                 unsigned short* __restrict__ vP, unsigned short* __restrict__ BP,
                 float* __restrict__ S) {
    __shared__ float tile[64][132];
    __shared__ float vsL[256];
    const int tid = threadIdx.x;
    const int bx  = blockIdx.x;
    if (bx < 256) {
        const int h = bx >> 4, jt = bx & 15;
        char* hiT = (char*)kPhi + (size_t)(h * 16 + jt) * 8192;
        char* loT = (char*)kPlo + (size_t)(h * 16 + jt) * 8192;
        const int row = tid >> 2;
        const int s0  = (tid & 3) * 16;
        const float* src = k_w + ((size_t)(h * NL + jt * 64 + row)) * HD + s0;
#pragma unroll
        for (int t = 0; t < 4; ++t) {
            float4 x = reinterpret_cast<const float4*>(src)[t];
            unsigned short h0, h1, h2, h3, l0, l1, l2, l3;
            bfsplit(x.x, h0, l0); bfsplit(x.y, h1, l1);
            bfsplit(x.z, h2, l2); bfsplit(x.w, h3, l3);
            int off = (row * 128 + (s0 + 4 * t) * 2) ^ ((row & 7) << 4);
            *(uint2*)(hiT + off) = make_uint2((u32)h0 | ((u32)h1 << 16),
                                              (u32)h2 | ((u32)h3 << 16));
            *(uint2*)(loT + off) = make_uint2((u32)l0 | ((u32)l1 << 16),
                                              (u32)l2 | ((u32)l3 << 16));
        }
    } else if (bx < 512) {
        const int h = (bx - 256) >> 4, jt = (bx - 256) & 15;
#pragma unroll
        for (int t = 0; t < 4; ++t) {
            int id = tid + 256 * t;
            int j = id >> 4, t4 = (id & 15) * 4;
            *(float4*)&tile[j][t4] =
                *(const float4*)(v_w + ((size_t)(h * NL + jt * 64 + j)) * HD + t4);
        }
        vsL[tid] = sums[2 * NB * NL + (tid >> 6) * NL + jt * 64 + (tid & 63)];
        __syncthreads();
        char* vT_ = (char*)vP + (size_t)(h * 16 + jt) * 8192;
        const int trow = tid >> 2;
        const int jq   = (tid & 3) * 16;
#pragma unroll
        for (int q = 0; q < 4; ++q) {
            int j4 = jq + 4 * q;
            uint2 u;
            u.x = (u32)f2bf(tile[j4 + 0][trow]) | ((u32)f2bf(tile[j4 + 1][trow]) << 16);
            u.y = (u32)f2bf(tile[j4 + 2][trow]) | ((u32)f2bf(tile[j4 + 3][trow]) << 16);
            int off = (trow * 128 + j4 * 2) ^ ((trow & 7) << 4);
            *(uint2*)(vT_ + off) = u;
        }
        if (jt >= 1) {
            const int b = tid >> 6, t = tid & 63;
            float a = 0.f;
#pragma unroll 16
            for (int j = 0; j < 64; ++j)
                a = fmaf(vsL[b * 64 + j], tile[j][t], a);
            S[(((size_t)h * 16 + jt) * 4 + b) * 64 + t] = a;
        }
    } else {
        const int bxo = bx - 512;
        const int ot = bxo >> 4, kt = bxo & 15;
#pragma unroll
        for (int t = 0; t < 8; ++t) {
            int id = tid + 256 * t;
            int c = id >> 5, o4 = (id & 31) * 4;
            *(float4*)&tile[c][o4] =
                *(const float4*)(o_w + ((size_t)(kt * 64 + c)) * ND + ot * 128 + o4);
        }
        __syncthreads();
        char* bT = (char*)BP + (size_t)(ot * 16 + kt) * 16384;
#pragma unroll
        for (int t = 0; t < 8; ++t) {
            int id = tid + 256 * t;
            int ol = id >> 4, c4 = (id & 15) * 4;
            uint2 u;
            u.x = (u32)f2bf(tile[c4 + 0][ol]) | ((u32)f2bf(tile[c4 + 1][ol]) << 16);
            u.y = (u32)f2bf(tile[c4 + 2][ol]) | ((u32)f2bf(tile[c4 + 3][ol]) << 16);
            int off = (ol * 128 + c4 * 2) ^ ((ol & 7) << 4);
            *(uint2*)(bT + off) = u;
        }
    }
}

// ---------------------------------------------------------------------------
// Kernel 3: fused attn with causal-tile skip.
// G computed as mfma(A=K, B=Q) so each thread owns 1 i x 4 consecutive j:
// softmax weights write as 4x ds_write_b64 (one per batch plane).
// ---------------------------------------------------------------------------
__global__ __launch_bounds__(512, 4)
void attn_kernel(const float* __restrict__ q_w, const int* __restrict__ pad,
                 const float* __restrict__ sums,
                 const unsigned short* __restrict__ kPhi,
                 const unsigned short* __restrict__ kPlo,
                 const unsigned short* __restrict__ vP,
                 const float* __restrict__ S,
                 unsigned short* __restrict__ AP) {
    __shared__ __align__(16) unsigned short kHi[2][4096], kLo[2][4096], vTl[2][4096];
    __shared__ __align__(16) unsigned short qHi[2048], qLo[2048];
    __shared__ __align__(16) unsigned short wlds[8192];
    __shared__ __align__(16) float qs4[128];
    __shared__ __align__(16) float ks4[2][256];
    __shared__ __align__(16) float vs4[2][256];
    __shared__ __align__(16) int   pm4[2][256];

    const float* qsum = sums;
    const float* ksum = sums + NB * NL;
    const float* vsum = sums + 2 * NB * NL;

    const int wid = blockIdx.x;
    const int gq  = wid >> 4;
    const int h   = wid & 15;
    const int itp = (gq < 16) ? (2 * gq) : (63 - 2 * gq);  // work-balanced remap
    const int it0 = itp * 32;
    const int cut = (it0 >> 6) + 1;

    const int tid  = threadIdx.x;
    const int lane = tid & 63;
    const int w    = tid >> 6;
    const int l15  = lane & 15;
    const int kb   = (lane >> 4) * 16;

    // ---- stage q tile (f32 -> bf16 hi/lo, swizzled), once ----
    {
        int row = tid >> 4;
        int s4  = (tid & 15) * 4;
        float4 x = *(const float4*)(q_w + ((size_t)(h * NL + it0 + row)) * HD + s4);
        unsigned short h0, h1, h2, h3, l0, l1, l2, l3;
        bfsplit(x.x, h0, l0); bfsplit(x.y, h1, l1);
        bfsplit(x.z, h2, l2); bfsplit(x.w, h3, l3);
        int off = (row * 128 + s4 * 2) ^ ((row & 7) << 4);
        *(uint2*)((char*)qHi + off) = make_uint2((u32)h0 | ((u32)h1 << 16),
                                                 (u32)h2 | ((u32)h3 << 16));
        *(uint2*)((char*)qLo + off) = make_uint2((u32)l0 | ((u32)l1 << 16),
                                                 (u32)l2 | ((u32)l3 << 16));
    }
    if (tid < 128) {
        int b = tid >> 5, i = tid & 31;
        qs4[i * 4 + b] = qsum[b * NL + it0 + i];
    }

    auto stage = [&](int buf, int jt) {
        const size_t tb = (size_t)(h * 16 + jt) * 8192 + tid * 16;
        gload16((char*)kHi[buf] + tid * 16, (const char*)kPhi + tb);
        gload16((char*)kLo[buf] + tid * 16, (const char*)kPlo + tb);
        gload16((char*)vTl[buf] + tid * 16, (const char*)vP + tb);
        if (tid < 256) {
            int b = tid >> 6, jj = tid & 63;
            ks4[buf][jj * 4 + b] = ksum[b * NL + jt * 64 + jj] * (LOG2E * 0.25f);
            vs4[buf][jj * 4 + b] = vsum[b * NL + jt * 64 + jj];
            pm4[buf][jj * 4 + b] = pad[b * NL + jt * 64 + jj];
        }
    };

    const int gmi = (w & 1) * 16;     // i-frag base (B operand)
    const int gnj = (w >> 1) * 16;    // j-frag base (A operand)
    const int pb  = w >> 1;
    const int pmh = (w & 1) * 16;

    f32x4 accP[4];
#pragma unroll
    for (int n = 0; n < 4; ++n) accP[n] = (f32x4){0.f, 0.f, 0.f, 0.f};

    stage(0, 0);
    __syncthreads();
    int cur = 0;

    // per-thread softmax geometry (fixed i, 4 consecutive j per tile)
    const int i_sm  = gmi + l15;
    const int ig    = it0 + i_sm;
    const int jb_sm = gnj + (lane >> 4) * 4;
    const float4 qsv = *(const float4*)&qs4[i_sm * 4];
    const int woff = (i_sm * 128 + jb_sm * 2) ^ ((i_sm & 7) << 4);

    for (int jt = 0; jt < cut; ++jt) {
        const int j0 = jt * 64;
        if (jt + 1 < cut) stage(cur ^ 1, jt + 1);

        // ---- G: one 16x16 fragment per wave, bf16x3, A=K B=Q ----
        f32x4 g = (f32x4){0.f, 0.f, 0.f, 0.f};
#pragma unroll
        for (int ks = 0; ks < 2; ++ks) {
            const int arow = gnj + l15;   // K rows (A)
            const int brow = gmi + l15;   // Q rows (B)
            const int aoff = (arow * 128 + ks * 64 + kb) ^ ((arow & 7) << 4);
            const int boff = (brow * 128 + ks * 64 + kb) ^ ((brow & 7) << 4);
            bf16x8 kHiF = __builtin_bit_cast(bf16x8, *(const uint4*)((const char*)kHi[cur] + aoff));
            bf16x8 kLoF = __builtin_bit_cast(bf16x8, *(const uint4*)((const char*)kLo[cur] + aoff));
            bf16x8 qHiF = __builtin_bit_cast(bf16x8, *(const uint4*)((const char*)qHi + boff));
            bf16x8 qLoF = __builtin_bit_cast(bf16x8, *(const uint4*)((const char*)qLo + boff));
            g = __builtin_amdgcn_mfma_f32_16x16x32_bf16(kHiF, qHiF, g, 0, 0, 0);
            g = __builtin_amdgcn_mfma_f32_16x16x32_bf16(kLoF, qHiF, g, 0, 0, 0);
            g = __builtin_amdgcn_mfma_f32_16x16x32_bf16(kHiF, qLoF, g, 0, 0, 0);
        }

        // ---- per-lane 4-batch softmax (exp2 domain); C row r = j, col = i ----
        {
            float wv[4][4];   // [r][b]
#pragma unroll
            for (int r = 0; r < 4; ++r) {
                const int j  = jb_sm + r;
                const int jg = j0 + j;
                const float4 ksv = *(const float4*)&ks4[cur][j * 4];
                const float4 vsv = *(const float4*)&vs4[cur][j * 4];
                const int4   pmv = *(const int4*)&pm4[cur][j * 4];
                const float gr = g[r];
                const bool causal = jg > ig;
                const float sb0 = (causal || pmv.x) ? FMIN_F32 : qsv.x * ksv.x * gr;
                const float sb1 = (causal || pmv.y) ? FMIN_F32 : qsv.y * ksv.y * gr;
                const float sb2 = (causal || pmv.z) ? FMIN_F32 : qsv.z * ksv.z * gr;
                const float sb3 = (causal || pmv.w) ? FMIN_F32 : qsv.w * ksv.w * gr;
                const float mx = fmaxf(fmaxf(sb0, sb1), fmaxf(sb2, sb3));
                const float e0 = __builtin_amdgcn_exp2f(sb0 - mx);
                const float e1 = __builtin_amdgcn_exp2f(sb1 - mx);
                const float e2 = __builtin_amdgcn_exp2f(sb2 - mx);
                const float e3 = __builtin_amdgcn_exp2f(sb3 - mx);
                const float inv = __builtin_amdgcn_rcpf((e0 + e1) + (e2 + e3));
                wv[r][0] = e0 * inv * vsv.x;
                wv[r][1] = e1 * inv * vsv.y;
                wv[r][2] = e2 * inv * vsv.z;
                wv[r][3] = e3 * inv * vsv.w;
            }
#pragma unroll
            for (int b = 0; b < 4; ++b) {
                uint2 p;
                p.x = (u32)f2bf(wv[0][b]) | ((u32)f2bf(wv[1][b]) << 16);
                p.y = (u32)f2bf(wv[2][b]) | ((u32)f2bf(wv[3][b]) << 16);
                *(uint2*)((char*)wlds + b * 4096 + woff) = p;
            }
        }
        // ---- barrier A: wlds visible; do NOT drain in-flight jt+1 stages ----
        asm volatile("s_waitcnt lgkmcnt(0)" ::: "memory");
        __builtin_amdgcn_s_barrier();
        __builtin_amdgcn_sched_barrier(0);

        // ---- PV: wave (pb, pmh): 16 i-rows x 64 t for batch pb ----
#pragma unroll
        for (int ks = 0; ks < 2; ++ks) {
            const int arow = pmh + l15;
            const int aoff = pb * 4096 + ((arow * 128 + ks * 64 + kb) ^ ((arow & 7) << 4));
            bf16x8 aF = __builtin_bit_cast(bf16x8, *(const uint4*)((const char*)wlds + aoff));
#pragma unroll
            for (int n = 0; n < 4; ++n) {
                const int vrow = n * 16 + l15;
                const int voff = (vrow * 128 + ks * 64 + kb) ^ ((vrow & 7) << 4);
                bf16x8 bF = __builtin_bit_cast(bf16x8, *(const uint4*)((const char*)vTl[cur] + voff));
                accP[n] = __builtin_amdgcn_mfma_f32_16x16x32_bf16(aF, bF, accP[n], 0, 0, 0);
            }
        }
        __syncthreads();   // full drain: stages landed, PV/wlds reads done
        cur ^= 1;
    }

    // ---- add fully-masked causal suffix: 0.25 * sum_{jt>=cut} S[h][jt][pb][t] ----
    if (cut < 16) {
        float sv[4] = {0.f, 0.f, 0.f, 0.f};
        for (int jt = cut; jt < 16; ++jt) {
            const float* sp = S + (((size_t)h * 16 + jt) * 4 + pb) * 64;
#pragma unroll
            for (int n = 0; n < 4; ++n) sv[n] += sp[n * 16 + l15];
        }
#pragma unroll
        for (int n = 0; n < 4; ++n) {
            const float s4v = 0.25f * sv[n];
#pragma unroll
            for (int r = 0; r < 4; ++r) accP[n][r] += s4v;
        }
    }

    // ---- store AP tiles (pre-swizzled out-GEMM A layout, bf16) ----
    {
        const int ib = (it0 + pmh) >> 4;
        char* tbase = (char*)AP + (size_t)((pb * 16 + h) * 16) * 8192;
#pragma unroll
        for (int n = 0; n < 4; ++n)
#pragma unroll
            for (int r = 0; r < 4; ++r) {
                int kt = (lane >> 4) * 4 + r;
                int tt = n * 16 + l15;
                int off = (ib * 128 + tt * 2) ^ ((ib & 7) << 4);
                *(unsigned short*)(tbase + (size_t)kt * 8192 + off) = f2bf(accP[n][r]);
            }
    }
}

// ---------------------------------------------------------------------------
// Kernel 4: out(4096x1024) = AP @ BP. 64x128 tiles, grid (8,64), 256 threads.
// T3/T4: 3 LDS buffers, stage 2 tiles ahead, counted s_waitcnt vmcnt(6) —
// only the oldest stage must land at each barrier; newer stages stay in flight.
// ---------------------------------------------------------------------------
__global__ __launch_bounds__(256, 2)
void outgemm_kernel(const unsigned short* __restrict__ AP,
                    const unsigned short* __restrict__ BP,
                    float* __restrict__ out) {
    __shared__ __align__(16) unsigned short aL[3][4096];   // 3 x 8KB
    __shared__ __align__(16) unsigned short bL[3][8192];   // 3 x 16KB
    const int ox = blockIdx.x;
    const int my = blockIdx.y;
    const int tid  = threadIdx.x;
    const int lane = tid & 63;
    const int w    = tid >> 6;
    const int wr = (w & 1) * 32;
    const int wc = (w >> 1) * 64;
    const int l15  = lane & 15;
    const int kseg = (lane >> 4) * 16;

    f32x4 acc[2][4];
#pragma unroll
    for (int m = 0; m < 2; ++m)
#pragma unroll
        for (int n = 0; n < 4; ++n) acc[m][n] = (f32x4){0.f, 0.f, 0.f, 0.f};

    auto stage = [&](int buf, int kt) {
        const char* at = (const char*)AP + (size_t)(my * 16 + kt) * 8192;
        const char* bt = (const char*)BP + (size_t)(ox * 16 + kt) * 16384;
        gload16((char*)aL[buf] + tid * 16, at + tid * 16);
        gload16((char*)aL[buf] + 4096 + tid * 16, at + 4096 + tid * 16);
#pragma unroll
        for (int r = 0; r < 4; ++r)
            gload16((char*)bL[buf] + r * 4096 + tid * 16, bt + r * 4096 + tid * 16);
    };

    auto compute = [&](int cb) {
#pragma unroll
        for (int ks = 0; ks < 2; ++ks) {
            bf16x8 aF[2], bF[4];
#pragma unroll
            for (int m = 0; m < 2; ++m) {
                int row = wr + m * 16 + l15;
                int off = (row * 128 + ks * 64 + kseg) ^ ((row & 7) << 4);
                aF[m] = __builtin_bit_cast(bf16x8, *(const uint4*)((const char*)aL[cb] + off));
            }
#pragma unroll
            for (int n = 0; n < 4; ++n) {
                int row = wc + n * 16 + l15;
                int off = (row * 128 + ks * 64 + kseg) ^ ((row & 7) << 4);
                bF[n] = __builtin_bit_cast(bf16x8, *(const uint4*)((const char*)bL[cb] + off));
            }
#pragma unroll
            for (int m = 0; m < 2; ++m)
#pragma unroll
                for (int n = 0; n < 4; ++n)
                    acc[m][n] = __builtin_amdgcn_mfma_f32_16x16x32_bf16(
                        aF[m], bF[n], acc[m][n], 0, 0, 0);
        }
    };

    stage(0, 0);
    stage(1, 1);
    for (int kt = 0; kt < 15; ++kt) {
        // wait: oldest stage (kt) landed; stage(kt+1) may stay in flight (6 ops)
        asm volatile("s_waitcnt vmcnt(6)" ::: "memory");
        __builtin_amdgcn_s_barrier();
        __builtin_amdgcn_sched_barrier(0);
        if (kt + 2 < 16) stage((kt + 2) % 3, kt + 2);
        compute(kt % 3);
    }
    asm volatile("s_waitcnt vmcnt(0)" ::: "memory");
    __builtin_amdgcn_s_barrier();
    __builtin_amdgcn_sched_barrier(0);
    compute(15 % 3);

#pragma unroll
    for (int m = 0; m < 2; ++m)
#pragma unroll
        for (int n = 0; n < 4; ++n)
#pragma unroll
            for (int r = 0; r < 4; ++r) {
                int row = my * 64 + wr + m * 16 + (lane >> 4) * 4 + r;
                int col = ox * 128 + wc + n * 16 + l15;
                out[(size_t)row * ND + col] = acc[m][n][r];
            }
}

// ---------------------------------------------------------------------------
extern "C" void kernel_launch(void* const* d_in, const int* in_sizes, int n_in,
                              void* d_out, int out_size, void* d_ws, size_t ws_size,
                              hipStream_t stream) {
    const float* query = (const float*)d_in[0];
    const float* key   = (const float*)d_in[1];
    const float* value = (const float*)d_in[2];
    const int*   pad   = (const int*)d_in[3];
    const float* q_w   = (const float*)d_in[4];
    const float* k_w   = (const float*)d_in[5];
    const float* v_w   = (const float*)d_in[6];
    const float* o_w   = (const float*)d_in[7];
    float* out = (float*)d_out;

    char* W = (char*)d_ws;
    float*          sums = (float*)W;                        // 48 KB
    unsigned short* kPhi = (unsigned short*)(W + 49152);     // 2 MB
    unsigned short* kPlo = (unsigned short*)(W + 2146304);   // 2 MB
    unsigned short* vP   = (unsigned short*)(W + 4243456);   // 2 MB
    unsigned short* BP   = (unsigned short*)(W + 6340608);   // 2 MB
    unsigned short* AP   = (unsigned short*)(W + 8437760);   // 8 MB

    float* S = out;   // 256 KB scratch in d_out; overwritten by outgemm

    rowsum_kernel<<<3 * (NB * NL) / 4, 256, 0, stream>>>(query, key, value, sums);

    prep_kernel<<<640, 256, 0, stream>>>(k_w, v_w, o_w, sums, kPhi, kPlo, vP, BP, S);

    attn_kernel<<<512, 512, 0, stream>>>(q_w, pad, sums, kPhi, kPlo, vP, S, AP);

    dim3 gg(8, 64);
    outgemm_kernel<<<gg, 256, 0, stream>>>(AP, BP, out);
}